// Round 1
// baseline (64525.140 us; speedup 1.0000x reference)
//
#include <hip/hip_runtime.h>
#include <math.h>

// Problem constants (fixed by the reference)
#define NV 20000
#define NH 512
#define NT 1024
#define NB 32
#define MAXD 64

// LSTM persistent-kernel geometry
#define NGRP 8      // groups (independent batch-row sets), sync domain = 1 group
#define BPG 32      // blocks per group
#define BPB 4       // batch rows per group  (NB / NGRP)
#define UPB 16      // hidden units per block (NH / BPG)
#define NJ 64       // gate rows per block = 4*UPB
#define KTOT 1024   // 2*NH
#define NTH 512
#define KPT 32      // k elements per thread slice

// ws layout: [ path: NV*NH f32 | hbuf: 2*NB*NH f32 | flags: 256 ints ]  ~= 41.1 MB

__global__ void init_kernel(float* __restrict__ hbuf, int* __restrict__ flags) {
  int i = blockIdx.x * blockDim.x + threadIdx.x;
  if (i < 2 * NB * NH) hbuf[i] = 0.f;
  if (i < 256) flags[i] = 0;
}

// One block per node: all 256 threads walk the same parent chain (uniform),
// each thread accumulates 2 of the 512 embedding columns (coalesced).
__global__ __launch_bounds__(256)
void path_kernel(const int* __restrict__ parents,
                 const float* __restrict__ weight,
                 const float* __restrict__ emb,
                 float* __restrict__ path) {
  int v = blockIdx.x;
  int h = threadIdx.x;
  float acc0 = 0.f, acc1 = 0.f;
  float w = 1.f;
  int cur = v;
#pragma unroll 1
  for (int d = 0; d < MAXD; ++d) {
    if (cur < 0) break;
    const float* row = emb + (size_t)cur * NH;
    acc0 = fmaf(w, row[h], acc0);
    acc1 = fmaf(w, row[h + 256], acc1);
    w *= weight[cur];
    cur = parents[cur];
  }
  path[(size_t)v * NH + h] = acc0;
  path[(size_t)v * NH + h + 256] = acc1;
}

// Persistent LSTM: 256 blocks = 8 groups x 32 blocks.
// Group g (blocks with blockIdx%8==g -> same XCD heuristic) owns batch rows
// [4g, 4g+4); block within group owns hidden units [16*blk, 16*blk+16), i.e.
// 64 gate rows. gate_w slice lives in registers (4 rows x 32 k per thread).
__global__ __launch_bounds__(NTH, 2)
void lstm_kernel(const int* __restrict__ ev,
                 const float* __restrict__ path,
                 const float* __restrict__ gate_w,
                 const float* __restrict__ gate_b,
                 float* __restrict__ hbuf,   // [2][NB][NH]
                 int* __restrict__ flags,    // per-group monotonic barrier ctr
                 float* __restrict__ out) {  // [3][NT][NB][NH]
  // in_s padded with one extra float per 32 (f(k)=k+(k>>5)) -> conflict-free
  __shared__ float in_s[BPB][KTOT + KTOT / 32];
  __shared__ float p_s[KPT][NJ * BPB + 1];   // stride 257 -> conflict-free
  __shared__ float zred[NJ * BPB];
  __shared__ float c_s[BPB][UPB];

  const int bid = blockIdx.x;
  const int grp = bid & 7;
  const int blk = bid >> 3;
  const int b0 = grp * BPB;
  const int u0 = blk * UPB;
  const int tid = threadIdx.x;
  const int jg = tid >> 5;   // 0..15: which 4-row group
  const int ks = tid & 31;   // 0..31: which 32-wide k slice

  // Load this thread's gate_w slice into registers (reused for all 1024 steps).
  float w[4][KPT];
#pragma unroll
  for (int jj = 0; jj < 4; ++jj) {
    int r = jg * 4 + jj;                        // 0..63: gate*16 + uu
    int j = (r >> 4) * NH + u0 + (r & 15);      // global gate row
    const float* wr = gate_w + (size_t)j * KTOT + ks * KPT;
#pragma unroll
    for (int kk = 0; kk < KPT; ++kk) w[jj][kk] = wr[kk];
  }

  if (tid < BPB * UPB) c_s[tid >> 4][tid & 15] = 0.f;
  __syncthreads();

  const int sb = tid >> 7;     // staging: batch row
  const int seg = tid & 127;   // staging: 8-dword chunk
  const int c0 = seg * 8;
  int* flagp = &flags[grp * 16];
  const size_t plane = (size_t)NT * NB * NH;

  for (int t = 0; t < NT; ++t) {
    const int par = t & 1;
    // ---- stage in = [x_t | h_{t-1}] for this group's 4 batch rows ----
    {
      int e = ev[t * NB + b0 + sb];
      const float* src = (c0 < NH)
          ? (path + (size_t)e * NH + c0)
          : (hbuf + ((size_t)par * NB + (b0 + sb)) * NH + (c0 - NH));
      float4 v0 = *(const float4*)(src);
      float4 v1 = *(const float4*)(src + 4);
      float* dst = &in_s[sb][0];
      int f0 = c0 + (c0 >> 5);
      dst[f0 + 0] = v0.x; dst[f0 + 1] = v0.y; dst[f0 + 2] = v0.z; dst[f0 + 3] = v0.w;
      dst[f0 + 4] = v1.x; dst[f0 + 5] = v1.y; dst[f0 + 6] = v1.z; dst[f0 + 7] = v1.w;
    }
    __syncthreads();

    // ---- partial GEMM: acc[jj][bi] over this thread's 32-k slice ----
    float acc[4][BPB];
#pragma unroll
    for (int jj = 0; jj < 4; ++jj)
#pragma unroll
      for (int bi = 0; bi < BPB; ++bi) acc[jj][bi] = 0.f;
    const int fb = ks * (KPT + 1);  // f(ks*32) = ks*33
#pragma unroll
    for (int bi = 0; bi < BPB; ++bi) {
      const float* inp = &in_s[bi][fb];
#pragma unroll
      for (int kk = 0; kk < KPT; ++kk) {
        float x = inp[kk];
        acc[0][bi] = fmaf(w[0][kk], x, acc[0][bi]);
        acc[1][bi] = fmaf(w[1][kk], x, acc[1][bi]);
        acc[2][bi] = fmaf(w[2][kk], x, acc[2][bi]);
        acc[3][bi] = fmaf(w[3][kk], x, acc[3][bi]);
      }
    }
#pragma unroll
    for (int jj = 0; jj < 4; ++jj) {
      int r = jg * 4 + jj;
#pragma unroll
      for (int bi = 0; bi < BPB; ++bi)
        p_s[ks][r * BPB + bi] = acc[jj][bi];
    }
    __syncthreads();

    // ---- reduce k-slices + bias ----
    if (tid < NJ * BPB) {
      float s = 0.f;
#pragma unroll
      for (int k2 = 0; k2 < KPT; ++k2) s += p_s[k2][tid];
      int r = tid >> 2;
      s += gate_b[(r >> 4) * NH + u0 + (r & 15)];
      zred[tid] = s;
    }
    __syncthreads();

    // ---- gates + state update + outputs ----
    if (tid < BPB * UPB) {
      int bi = tid >> 4, uu = tid & 15;
      float zi = zred[(uu) * BPB + bi];
      float zf = zred[(UPB + uu) * BPB + bi];
      float zg = zred[(2 * UPB + uu) * BPB + bi];
      float zo = zred[(3 * UPB + uu) * BPB + bi];
      float ig = 1.f / (1.f + expf(-zi));
      float fg = 1.f / (1.f + expf(-zf));
      float gg = tanhf(zg);
      float og = 1.f / (1.f + expf(-zo));
      float c = fmaf(fg, c_s[bi][uu], ig * gg);
      float h = og * tanhf(c);
      c_s[bi][uu] = c;
      int b = b0 + bi, u = u0 + uu;
      size_t o0 = ((size_t)t * NB + b) * NH + u;
      out[o0] = h;
      out[plane + o0] = c;
      out[2 * plane + o0] = og;
      if (t + 1 < NT) hbuf[((size_t)((t + 1) & 1) * NB + b) * NH + u] = h;
      __threadfence();  // make h visible at device scope before arrival
    }
    __syncthreads();

    // ---- group barrier (32 blocks): monotonic counter ----
    if (t + 1 < NT) {
      if (tid == 0)
        __hip_atomic_fetch_add(flagp, 1, __ATOMIC_RELEASE, __HIP_MEMORY_SCOPE_AGENT);
      const int target = BPG * (t + 1);
      while (__hip_atomic_load(flagp, __ATOMIC_RELAXED, __HIP_MEMORY_SCOPE_AGENT) < target)
        __builtin_amdgcn_s_sleep(1);
      __threadfence();  // acquire: invalidate stale h before next stage
    }
  }
}

extern "C" void kernel_launch(void* const* d_in, const int* in_sizes, int n_in,
                              void* d_out, int out_size, void* d_ws, size_t ws_size,
                              hipStream_t stream) {
  const int* ev = (const int*)d_in[0];
  const int* parents = (const int*)d_in[1];
  const float* weight = (const float*)d_in[2];
  const float* emb = (const float*)d_in[3];
  const float* gate_w = (const float*)d_in[4];
  const float* gate_b = (const float*)d_in[5];
  float* out = (float*)d_out;

  char* ws = (char*)d_ws;
  float* path = (float*)ws;
  size_t path_bytes = (size_t)NV * NH * sizeof(float);
  float* hbuf = (float*)(ws + path_bytes);
  int* flags = (int*)(ws + path_bytes + (size_t)2 * NB * NH * sizeof(float));

  init_kernel<<<(2 * NB * NH + 255) / 256, 256, 0, stream>>>(hbuf, flags);
  path_kernel<<<NV, 256, 0, stream>>>(parents, weight, emb, path);
  lstm_kernel<<<NGRP * BPG, NTH, 0, stream>>>(ev, path, gate_w, gate_b, hbuf, flags, out);
}

// Round 3
// 24523.486 us; speedup vs baseline: 2.6312x; 2.6312x over previous
//
#include <hip/hip_runtime.h>
#include <math.h>

// Problem constants (fixed by the reference)
#define NV 20000
#define NH 512
#define NT 1024
#define NB 32
#define MAXD 64

// LSTM persistent-kernel geometry
#define NGRP 8      // groups (independent batch-row sets), sync domain = 1 group
#define BPG 32      // blocks per group
#define BPB 4       // batch rows per group  (NB / NGRP)
#define UPB 16      // hidden units per block (NH / BPG)
#define NJ 64       // gate rows per block = 4*UPB
#define KTOT 1024   // 2*NH
#define NTH 512
#define KPT 32      // k elements per thread slice

// ws layout: [ path: NV*NH f32 | hbuf: 2*NB*NH f32 | flags: 256 ints ]  ~= 41.1 MB

__global__ void init_kernel(float* __restrict__ hbuf, int* __restrict__ flags) {
  int i = blockIdx.x * blockDim.x + threadIdx.x;
  if (i < 2 * NB * NH) hbuf[i] = 0.f;
  if (i < 256) flags[i] = 0;
}

// One block per node: all 256 threads walk the same parent chain (uniform),
// each thread accumulates 2 of the 512 embedding columns (coalesced).
__global__ __launch_bounds__(256)
void path_kernel(const int* __restrict__ parents,
                 const float* __restrict__ weight,
                 const float* __restrict__ emb,
                 float* __restrict__ path) {
  int v = blockIdx.x;
  int h = threadIdx.x;
  float acc0 = 0.f, acc1 = 0.f;
  float w = 1.f;
  int cur = v;
#pragma unroll 1
  for (int d = 0; d < MAXD; ++d) {
    if (cur < 0) break;
    const float* row = emb + (size_t)cur * NH;
    acc0 = fmaf(w, row[h], acc0);
    acc1 = fmaf(w, row[h + 256], acc1);
    w *= weight[cur];
    cur = parents[cur];
  }
  path[(size_t)v * NH + h] = acc0;
  path[(size_t)v * NH + h + 256] = acc1;
}

// Persistent LSTM: 256 blocks = 8 groups x 32 blocks.
// Group g owns batch rows [4g, 4g+4); block within group owns hidden units
// [16*blk, 16*blk+16), i.e. 64 gate rows. gate_w slice lives in registers.
// Barrier v2: wave 0 only. All hbuf producers are tid<64 (= wave 0), so a
// wave-0 release fence + single-lane arrival + single-lane poll + wave-0
// acquire fence + __syncthreads is a correct cross-XCD barrier regardless of
// block->XCD placement.
__global__ __launch_bounds__(NTH, 2)
void lstm_kernel(const int* __restrict__ ev,
                 const float* __restrict__ path,
                 const float* __restrict__ gate_w,
                 const float* __restrict__ gate_b,
                 float* __restrict__ hbuf,   // [2][NB][NH]
                 int* __restrict__ flags,    // per-group monotonic barrier ctr
                 float* __restrict__ out) {  // [3][NT][NB][NH]
  // in_s padded with one extra float per 32 (f(k)=k+(k>>5)) -> conflict-free
  __shared__ float in_s[BPB][KTOT + KTOT / 32];
  __shared__ float p_s[KPT][NJ * BPB + 1];   // stride 257 -> conflict-free
  __shared__ float zred[NJ * BPB];
  __shared__ float c_s[BPB][UPB];

  const int bid = blockIdx.x;
  const int grp = bid & 7;
  const int blk = bid >> 3;
  const int b0 = grp * BPB;
  const int u0 = blk * UPB;
  const int tid = threadIdx.x;
  const int jg = tid >> 5;   // 0..15: which 4-row group
  const int ks = tid & 31;   // 0..31: which 32-wide k slice

  // Load this thread's gate_w slice into registers (reused for all 1024 steps).
  float w[4][KPT];
#pragma unroll
  for (int jj = 0; jj < 4; ++jj) {
    int r = jg * 4 + jj;                        // 0..63: gate*16 + uu
    int j = (r >> 4) * NH + u0 + (r & 15);      // global gate row
    const float* wr = gate_w + (size_t)j * KTOT + ks * KPT;
#pragma unroll
    for (int kk = 0; kk < KPT; ++kk) w[jj][kk] = wr[kk];
  }

  if (tid < BPB * UPB) c_s[tid >> 4][tid & 15] = 0.f;
  __syncthreads();

  const int sb = tid >> 7;     // staging: batch row
  const int seg = tid & 127;   // staging: 8-dword chunk
  const int c0 = seg * 8;
  int* flagp = &flags[grp * 16];
  const size_t plane = (size_t)NT * NB * NH;

  for (int t = 0; t < NT; ++t) {
    const int par = t & 1;
    // ---- stage in = [x_t | h_{t-1}] for this group's 4 batch rows ----
    {
      int e = ev[t * NB + b0 + sb];
      const float* src = (c0 < NH)
          ? (path + (size_t)e * NH + c0)
          : (hbuf + ((size_t)par * NB + (b0 + sb)) * NH + (c0 - NH));
      float4 v0 = *(const float4*)(src);
      float4 v1 = *(const float4*)(src + 4);
      float* dst = &in_s[sb][0];
      int f0 = c0 + (c0 >> 5);
      dst[f0 + 0] = v0.x; dst[f0 + 1] = v0.y; dst[f0 + 2] = v0.z; dst[f0 + 3] = v0.w;
      dst[f0 + 4] = v1.x; dst[f0 + 5] = v1.y; dst[f0 + 6] = v1.z; dst[f0 + 7] = v1.w;
    }
    __syncthreads();   // A

    // ---- partial GEMM: acc[jj][bi] over this thread's 32-k slice ----
    float acc[4][BPB];
#pragma unroll
    for (int jj = 0; jj < 4; ++jj)
#pragma unroll
      for (int bi = 0; bi < BPB; ++bi) acc[jj][bi] = 0.f;
    const int fb = ks * (KPT + 1);  // f(ks*32) = ks*33
#pragma unroll
    for (int bi = 0; bi < BPB; ++bi) {
      const float* inp = &in_s[bi][fb];
#pragma unroll
      for (int kk = 0; kk < KPT; ++kk) {
        float x = inp[kk];
        acc[0][bi] = fmaf(w[0][kk], x, acc[0][bi]);
        acc[1][bi] = fmaf(w[1][kk], x, acc[1][bi]);
        acc[2][bi] = fmaf(w[2][kk], x, acc[2][bi]);
        acc[3][bi] = fmaf(w[3][kk], x, acc[3][bi]);
      }
    }
#pragma unroll
    for (int jj = 0; jj < 4; ++jj) {
      int r = jg * 4 + jj;
#pragma unroll
      for (int bi = 0; bi < BPB; ++bi)
        p_s[ks][r * BPB + bi] = acc[jj][bi];
    }
    __syncthreads();   // B

    // ---- reduce k-slices + bias ----
    if (tid < NJ * BPB) {
      float s = 0.f;
#pragma unroll
      for (int k2 = 0; k2 < KPT; ++k2) s += p_s[k2][tid];
      int r = tid >> 2;
      s += gate_b[(r >> 4) * NH + u0 + (r & 15)];
      zred[tid] = s;
    }
    __syncthreads();   // C

    // ---- gates + state update (wave 0 only: tid < 64) ----
    const bool more = (t + 1 < NT);
    float hv = 0.f, cv = 0.f, ogv = 0.f;
    int b = 0, u = 0;
    const bool gate_thread = tid < BPB * UPB;
    if (gate_thread) {
      int bi = tid >> 4, uu = tid & 15;
      float zi = zred[(uu) * BPB + bi];
      float zf = zred[(UPB + uu) * BPB + bi];
      float zg = zred[(2 * UPB + uu) * BPB + bi];
      float zo = zred[(3 * UPB + uu) * BPB + bi];
      float ig = 1.f / (1.f + expf(-zi));
      float fg = 1.f / (1.f + expf(-zf));
      float gg = tanhf(zg);
      ogv = 1.f / (1.f + expf(-zo));
      cv = fmaf(fg, c_s[bi][uu], ig * gg);
      hv = ogv * tanhf(cv);
      c_s[bi][uu] = cv;
      b = b0 + bi; u = u0 + uu;
      if (more) hbuf[((size_t)((t + 1) & 1) * NB + b) * NH + u] = hv;
    }

    // ---- arrive (wave 0): release covers wave 0's hbuf stores ----
    if (more && tid < 64) {
      __builtin_amdgcn_fence(__ATOMIC_RELEASE, "agent");
      if (tid == 0)
        __hip_atomic_fetch_add(flagp, 1, __ATOMIC_RELAXED, __HIP_MEMORY_SCOPE_AGENT);
    }

    // ---- output stores overlap the barrier wait window ----
    if (gate_thread) {
      size_t o0 = ((size_t)t * NB + b) * NH + u;
      out[o0] = hv;
      out[plane + o0] = cv;
      out[2 * plane + o0] = ogv;
    }

    // ---- single-lane poll + wave-0 acquire ----
    if (more && tid < 64) {
      if (tid == 0) {
        const int target = BPG * (t + 1);
        while (__hip_atomic_load(flagp, __ATOMIC_RELAXED, __HIP_MEMORY_SCOPE_AGENT) < target)
          __builtin_amdgcn_s_sleep(2);
      }
      __builtin_amdgcn_fence(__ATOMIC_ACQUIRE, "agent");
    }
    __syncthreads();   // E: release all waves into next step
  }
}

extern "C" void kernel_launch(void* const* d_in, const int* in_sizes, int n_in,
                              void* d_out, int out_size, void* d_ws, size_t ws_size,
                              hipStream_t stream) {
  const int* ev = (const int*)d_in[0];
  const int* parents = (const int*)d_in[1];
  const float* weight = (const float*)d_in[2];
  const float* emb = (const float*)d_in[3];
  const float* gate_w = (const float*)d_in[4];
  const float* gate_b = (const float*)d_in[5];
  float* out = (float*)d_out;

  char* ws = (char*)d_ws;
  float* path = (float*)ws;
  size_t path_bytes = (size_t)NV * NH * sizeof(float);
  float* hbuf = (float*)(ws + path_bytes);
  int* flags = (int*)(ws + path_bytes + (size_t)2 * NB * NH * sizeof(float));

  init_kernel<<<(2 * NB * NH + 255) / 256, 256, 0, stream>>>(hbuf, flags);
  path_kernel<<<NV, 256, 0, stream>>>(parents, weight, emb, path);
  lstm_kernel<<<NGRP * BPG, NTH, 0, stream>>>(ev, path, gate_w, gate_b, hbuf, flags, out);
}